// Round 2
// baseline (107.603 us; speedup 1.0000x reference)
//
#include <hip/hip_runtime.h>
#include <hip/hip_bf16.h>

#define NFEAT 256
#define NATOMS 4096
#define NCLAUSES 512
#define ROWS 8
#define XPAD 12          // floats per feature column: 8 rows + 4 pad -> 48B (16B aligned)
#define ATOMS_PER_THREAD 16
#define BLOCK 256

// hardware transcendentals: v_exp_f32 computes 2^x, v_log_f32 computes log2(x)
#define EXP2F(v) __builtin_amdgcn_exp2f(v)
#define LOG2F(v) __builtin_amdgcn_logf(v)

// Precompute per-atom fused constants and gate*leaf.
//   z = s*B*(w*x - eta + eps);  e = exp(-z) = exp2(A2*x + B2)
//   A2 = -s*B*log2(e)*w ;  B2 = s*B*log2(e)*(eta - eps)
__global__ void cln_pre(const float* __restrict__ w, const float* __restrict__ eta,
                        const float* __restrict__ leaf, const float* __restrict__ gate,
                        const int* __restrict__ fid, const int* __restrict__ sgn,
                        const int* __restrict__ cid,
                        float2* __restrict__ ab, int* __restrict__ pc,
                        float* __restrict__ gl) {
    int i = blockIdx.x * blockDim.x + threadIdx.x;
    const float K = 144.269504088896340736f;  // B_CONST * log2(e), B=100
    if (i < NATOMS) {
        float s = (sgn[i] == 0) ? -1.f : 1.f;
        float a2 = -s * K * w[i];
        float b2 =  s * K * (eta[i] - 0.01f);
        ab[i] = make_float2(a2, b2);
        pc[i] = (cid[i] << 16) | (fid[i] & 0xFFFF);
    }
    if (i < NCLAUSES) gl[i] = gate[i] * leaf[i];
}

__global__ __launch_bounds__(BLOCK, 4) void cln_main(
        const float* __restrict__ x, const float2* __restrict__ ab,
        const int* __restrict__ pc, const float* __restrict__ gl,
        float* __restrict__ y) {
    __shared__ __align__(16) float xT[NFEAT * XPAD];   // 12 KB, transposed x tile
    __shared__ float cl[ROWS * NCLAUSES];              // 16 KB, log2-domain clause sums

    const int tid = threadIdx.x;
    const int row0 = blockIdx.x * ROWS;

    // Stage 8 rows of x, transposed: xT[c*XPAD + r]. Coalesced global reads.
#pragma unroll
    for (int k = 0; k < ROWS; ++k) {
        float v = x[(row0 + k) * NFEAT + tid];
        xT[tid * XPAD + k] = v;
    }
    // Zero clause accumulators: 4096 floats / 256 threads
#pragma unroll
    for (int k = 0; k < (ROWS * NCLAUSES) / BLOCK; ++k)
        cl[k * BLOCK + tid] = 0.f;
    __syncthreads();

    // Each thread: 16 contiguous atoms (clause_ids sorted -> few boundary flushes).
    const int a0 = tid * ATOMS_PER_THREAD;
    float p[ROWS];
#pragma unroll
    for (int r = 0; r < ROWS; ++r) p[r] = 1.f;
    int cur = pc[a0] >> 16;

    for (int j = 0; j < ATOMS_PER_THREAD; ++j) {
        const int a = a0 + j;
        const int pcv = pc[a];
        const int cid = pcv >> 16;
        const int fidx = pcv & 0xFFFF;
        const float2 c = ab[a];
        if (cid != cur) {  // flush run product into clause accumulators
#pragma unroll
            for (int r = 0; r < ROWS; ++r) {
                atomicAdd(&cl[r * NCLAUSES + cur], LOG2F(p[r]));
                p[r] = 1.f;
            }
            cur = cid;
        }
        const float* xp = &xT[fidx * XPAD];
        const float4 xa = *(const float4*)(xp);
        const float4 xb = *(const float4*)(xp + 4);
        const float xv[ROWS] = {xa.x, xa.y, xa.z, xa.w, xb.x, xb.y, xb.z, xb.w};
#pragma unroll
        for (int r = 0; r < ROWS; ++r) {
            float e = EXP2F(fmaf(c.x, xv[r], c.y));
            // p *= (1+e); clamp to avoid inf (later inf*0 -> NaN). Clamped runs
            // give clause <= ~1e-37 ~ 0, matching ref underflow.
            p[r] = fminf(fmaf(p[r], e, p[r]), 1e37f);
        }
    }
#pragma unroll
    for (int r = 0; r < ROWS; ++r)
        atomicAdd(&cl[r * NCLAUSES + cur], LOG2F(p[r]));
    __syncthreads();

    // Final reduce: wave w handles rows 2w, 2w+1. y = sum_c gl[c]*exp2(-S[c]).
    const int wave = tid >> 6;
    const int lane = tid & 63;
#pragma unroll
    for (int rr = 0; rr < 2; ++rr) {
        const int r = wave * 2 + rr;
        float s = 0.f;
#pragma unroll
        for (int k = 0; k < NCLAUSES / 64; ++k) {
            const int cc = lane + k * 64;
            s += gl[cc] * EXP2F(-cl[r * NCLAUSES + cc]);
        }
#pragma unroll
        for (int off = 32; off > 0; off >>= 1)
            s += __shfl_down(s, off, 64);
        if (lane == 0) y[row0 + r] = s;
    }
}

extern "C" void kernel_launch(void* const* d_in, const int* in_sizes, int n_in,
                              void* d_out, int out_size, void* d_ws, size_t ws_size,
                              hipStream_t stream) {
    const float* x    = (const float*)d_in[0];
    const float* w    = (const float*)d_in[1];
    const float* eta  = (const float*)d_in[2];
    const float* leaf = (const float*)d_in[3];
    const float* gate = (const float*)d_in[4];
    const int*   fid  = (const int*)d_in[5];
    const int*   sgn  = (const int*)d_in[6];
    const int*   cid  = (const int*)d_in[7];
    float* y = (float*)d_out;

    char* ws = (char*)d_ws;
    float2* ab = (float2*)ws;                                // 32 KB
    int*    pc = (int*)(ws + NATOMS * sizeof(float2));       // 16 KB
    float*  gl = (float*)(ws + NATOMS * sizeof(float2) + NATOMS * sizeof(int)); // 2 KB

    const int bsz = in_sizes[0] / NFEAT;  // 8192

    cln_pre<<<NATOMS / BLOCK, BLOCK, 0, stream>>>(w, eta, leaf, gate, fid, sgn, cid,
                                                  ab, pc, gl);
    cln_main<<<bsz / ROWS, BLOCK, 0, stream>>>(x, ab, pc, gl, y);
}

// Round 4
// 94.011 us; speedup vs baseline: 1.1446x; 1.1446x over previous
//
#include <hip/hip_runtime.h>
#include <hip/hip_bf16.h>

#define NFEAT 256
#define NATOMS 4096
#define NCLAUSES 512
#define ROWS 8
#define XPAD 12          // floats per feature column: uniform LDS bank spread (gcd(12,32)=4 -> 8 groups x 4 banks)
#define BLOCK 256

// hardware transcendentals: v_exp_f32 computes 2^x
#define EXP2F(v) __builtin_amdgcn_exp2f(v)
#define RCPF(v)  __builtin_amdgcn_rcpf(v)

// Precompute:
//  - per-atom packed params abf[a] = {A, B, float_as_int(fid*XPAD), unused}
//    where e = exp(-z) = exp2(A*x + B);  A = -s*B_CONST*log2e*w ; B = s*B_CONST*log2e*(eta - eps)
//  - CSR clause offsets seg[0..512] via binary search over sorted clause_ids
//  - gl[c] = gate[c]*leaf[c]
__global__ void cln_pre(const float* __restrict__ w, const float* __restrict__ eta,
                        const float* __restrict__ leaf, const float* __restrict__ gate,
                        const int* __restrict__ fid, const int* __restrict__ sgn,
                        const int* __restrict__ cid,
                        float4* __restrict__ abf, int* __restrict__ seg,
                        float* __restrict__ gl) {
    int i = blockIdx.x * blockDim.x + threadIdx.x;
    const float K = 144.269504088896340736f;  // B_CONST * log2(e), B=100
    if (i < NATOMS) {
        float s = (sgn[i] == 0) ? -1.f : 1.f;
        float a2 = -s * K * w[i];
        float b2 =  s * K * (eta[i] - 0.01f);
        abf[i] = make_float4(a2, b2, __int_as_float(fid[i] * XPAD), 0.f);
    }
    if (i <= NCLAUSES) {
        // lower_bound: first index with cid[idx] >= i
        int lo = 0, hi = NATOMS;
        while (lo < hi) {
            int mid = (lo + hi) >> 1;
            if (cid[mid] < i) lo = mid + 1; else hi = mid;
        }
        seg[i] = lo;
    }
    if (i < NCLAUSES) gl[i] = gate[i] * leaf[i];
}

__global__ __launch_bounds__(BLOCK, 4) void cln_main(
        const float* __restrict__ x, const float4* __restrict__ abf,
        const int* __restrict__ seg, const float* __restrict__ gl,
        float* __restrict__ y) {
    __shared__ __align__(16) float xT[NFEAT * XPAD];   // 12 KB, transposed x tile; reused for reduce

    const int tid = threadIdx.x;
    const int row0 = blockIdx.x * ROWS;

    // Stage 8 rows of x, transposed: xT[fid*XPAD + r]. Coalesced global reads.
#pragma unroll
    for (int k = 0; k < ROWS; ++k) {
        float v = x[(row0 + k) * NFEAT + tid];
        xT[tid * XPAD + k] = v;
    }
    __syncthreads();

    float acc[ROWS];
#pragma unroll
    for (int r = 0; r < ROWS; ++r) acc[r] = 0.f;

    // Each thread owns 2 whole clauses: product t-norm accumulated directly,
    // no logs, no atomics, no divergent flush. p>=1 always. Clamp at 1e37:
    // without it, p=inf followed by ev=0 gives fmaf(inf,0,inf)=NaN (the R3 bug).
    // Clamped clause -> rcp ~ 1e-37 ~ 0, matching the reference's underflow.
#pragma unroll
    for (int cc = 0; cc < 2; ++cc) {
        const int c = (tid << 1) | cc;
        const int s = seg[c];
        const int e = seg[c + 1];
        float p[ROWS];
#pragma unroll
        for (int r = 0; r < ROWS; ++r) p[r] = 1.f;
        for (int a = s; a < e; ++a) {
            const float4 t = abf[a];
            const int xo = __float_as_int(t.z);
            const float4 xa = *(const float4*)(xT + xo);
            const float4 xb = *(const float4*)(xT + xo + 4);
            const float xv[ROWS] = {xa.x, xa.y, xa.z, xa.w, xb.x, xb.y, xb.z, xb.w};
#pragma unroll
            for (int r = 0; r < ROWS; ++r) {
                float ev = EXP2F(fmaf(t.x, xv[r], t.y));
                p[r] = fminf(fmaf(p[r], ev, p[r]), 1e37f);   // p *= (1 + e), clamped
            }
        }
        const float g = gl[c];
#pragma unroll
        for (int r = 0; r < ROWS; ++r)
            acc[r] = fmaf(g, RCPF(p[r]), acc[r]);
    }

    // Block reduction: wave shuffle-reduce each row, then 4 partials via LDS.
    __syncthreads();                 // xT no longer needed as x-tile
    float* red = xT;                 // 4 waves * 8 rows
    const int wave = tid >> 6;
    const int lane = tid & 63;
#pragma unroll
    for (int r = 0; r < ROWS; ++r) {
        float v = acc[r];
#pragma unroll
        for (int off = 32; off > 0; off >>= 1)
            v += __shfl_down(v, off, 64);
        if (lane == 0) red[wave * ROWS + r] = v;
    }
    __syncthreads();
    if (tid < ROWS) {
        float sres = red[tid] + red[ROWS + tid] + red[2 * ROWS + tid] + red[3 * ROWS + tid];
        y[row0 + tid] = sres;
    }
}

extern "C" void kernel_launch(void* const* d_in, const int* in_sizes, int n_in,
                              void* d_out, int out_size, void* d_ws, size_t ws_size,
                              hipStream_t stream) {
    const float* x    = (const float*)d_in[0];
    const float* w    = (const float*)d_in[1];
    const float* eta  = (const float*)d_in[2];
    const float* leaf = (const float*)d_in[3];
    const float* gate = (const float*)d_in[4];
    const int*   fid  = (const int*)d_in[5];
    const int*   sgn  = (const int*)d_in[6];
    const int*   cid  = (const int*)d_in[7];
    float* y = (float*)d_out;

    char* ws = (char*)d_ws;
    float4* abf = (float4*)ws;                                   // 64 KB
    int*    seg = (int*)(ws + NATOMS * sizeof(float4));          // 2052 B
    float*  gl  = (float*)(ws + NATOMS * sizeof(float4) + (NCLAUSES + 1 + 3) * sizeof(int)); // 2 KB

    const int bsz = in_sizes[0] / NFEAT;  // 8192

    cln_pre<<<NATOMS / BLOCK, BLOCK, 0, stream>>>(w, eta, leaf, gate, fid, sgn, cid,
                                                  abf, seg, gl);
    cln_main<<<bsz / ROWS, BLOCK, 0, stream>>>(x, abf, seg, gl, y);
}